// Round 1
// baseline (4453.927 us; speedup 1.0000x reference)
//
#include <hip/hip_runtime.h>

#define EPS_F 0.001f

constexpr int Nn = 16;
constexpr int Cc = 64;
constexpr int Tt = 64;
constexpr int Vv = 384;
constexpr size_t TV = (size_t)Tt * Vv;      // 24576
constexpr size_t VW = (size_t)Vv * Vv;      // 147456
constexpr size_t OUT0 = (size_t)Nn * Cc * TV;   // 25165824 floats (out)
// An: Nn*Cc*VW = 150994944 floats, appended after out in d_out

// ---------------- Kernel 1: xc[n,o,t,v] = sum_c x[n,c,t,v]*cw[o,c] + cb[o] ----
__global__ __launch_bounds__(256) void k_conv(const float* __restrict__ x,
        const float* __restrict__ cw, const float* __restrict__ cb,
        float* __restrict__ xc) {
    __shared__ float wt[64 * 64];   // transposed: wt[c*64+o]
    const int tid = threadIdx.x;
    for (int i = tid; i < 4096; i += 256) {
        int o = i & 63, c = i >> 6;
        wt[c * 64 + o] = cw[o * 64 + c];
    }
    __syncthreads();
    const int b = blockIdx.x;            // 768 blocks, 48 per n
    const int n = b / 48;
    const int pos = (b % 48) * 512 + tid;   // this thread handles pos and pos+256
    const float* xin = x + (size_t)n * Cc * TV + pos;
    float acc0[64], acc1[64];
#pragma unroll
    for (int o = 0; o < 64; ++o) { acc0[o] = 0.f; acc1[o] = 0.f; }
    for (int c = 0; c < 64; ++c) {
        float x0 = xin[(size_t)c * TV];
        float x1 = xin[(size_t)c * TV + 256];
        const float4* wr = (const float4*)(wt + c * 64);
#pragma unroll
        for (int oq = 0; oq < 16; ++oq) {
            float4 w4 = wr[oq];
            acc0[oq*4+0] += x0 * w4.x; acc0[oq*4+1] += x0 * w4.y;
            acc0[oq*4+2] += x0 * w4.z; acc0[oq*4+3] += x0 * w4.w;
            acc1[oq*4+0] += x1 * w4.x; acc1[oq*4+1] += x1 * w4.y;
            acc1[oq*4+2] += x1 * w4.z; acc1[oq*4+3] += x1 * w4.w;
        }
    }
    float* xo = xc + (size_t)n * Cc * TV + pos;
#pragma unroll
    for (int o = 0; o < 64; ++o) {
        float bo = cb[o];
        xo[(size_t)o * TV]       = acc0[o] + bo;
        xo[(size_t)o * TV + 256] = acc1[o] + bo;
    }
}

// ---------------- MLP layers 1-2 (weights via uniform/scalar loads) ----------
__device__ __forceinline__ void mlp12(const float a[8],
        const float* __restrict__ w1, const float* __restrict__ b1,
        const float* __restrict__ w2, const float* __restrict__ b2,
        float h2[32]) {
    float h1[16];
#pragma unroll
    for (int o = 0; o < 16; ++o) {
        float t = b1[o];
#pragma unroll
        for (int k = 0; k < 7; ++k) t += w1[o * 7 + k] * a[k];
        h1[o] = fmaxf(t, 0.f);
    }
#pragma unroll
    for (int o = 0; o < 32; ++o) {
        float t = b2[o];
#pragma unroll
        for (int i = 0; i < 16; ++i) t += w2[o * 16 + i] * h1[i];
        h2[o] = fmaxf(t, 0.f);
    }
}

// ---------------- Kernel 2a: Dl[n,c,w] += sum over a v-chunk of Am -----------
__global__ __launch_bounds__(128) void k_dl(const float* __restrict__ A,
        const float* __restrict__ w1, const float* __restrict__ b1,
        const float* __restrict__ w2, const float* __restrict__ b2,
        const float* __restrict__ w3, const float* __restrict__ b3,
        float* __restrict__ Dl) {
    const int tid = threadIdx.x;
    const int b = blockIdx.x;            // n(16) x wtile(3) x vchunk(32)
    const int n = b / 96;
    const int wt = (b % 96) / 32;
    const int vc = b % 32;
    const int w = wt * 128 + tid;
    const float* Ab = A + (size_t)n * 8 * VW + w;
    float cs[64];
#pragma unroll
    for (int o = 0; o < 64; ++o) cs[o] = 0.f;
    for (int v = vc * 12; v < vc * 12 + 12; ++v) {
        float a[8];
#pragma unroll
        for (int k = 0; k < 8; ++k) a[k] = Ab[(size_t)k * VW + (size_t)v * Vv];
        float h2[32];
        mlp12(a, w1, b1, w2, b2, h2);
        const float mask = a[7];
#pragma unroll
        for (int o = 0; o < 64; ++o) {
            float t = b3[o];
#pragma unroll
            for (int i = 0; i < 32; ++i) t += w3[o * 32 + i] * h2[i];
            cs[o] += fmaxf(t, 0.f) * mask;
        }
    }
    float* dp = Dl + (size_t)n * 64 * Vv + w;
#pragma unroll
    for (int o = 0; o < 64; ++o) atomicAdd(dp + (size_t)o * Vv, cs[o]);
}

// ---------------- Kernel 2a2: Dl -> 1/(Dl+eps) -------------------------------
__global__ __launch_bounds__(256) void k_rcp(float* __restrict__ Dl) {
    size_t i = (size_t)blockIdx.x * 256 + threadIdx.x;
    Dl[i] = 1.f / (Dl[i] + EPS_F);
}

// ---------------- Kernel 2b: An[n,c,v,w] = relu(mlp)*mask*Dlr[n,c,w] ---------
__global__ __launch_bounds__(384) void k_an(const float* __restrict__ A,
        const float* __restrict__ w1, const float* __restrict__ b1,
        const float* __restrict__ w2, const float* __restrict__ b2,
        const float* __restrict__ w3, const float* __restrict__ b3,
        const float* __restrict__ Dlr, float* __restrict__ An) {
    const int tid = threadIdx.x;        // w
    const int b = blockIdx.x;           // n*384 + v
    const int n = b / 384;
    const int v = b % 384;
    const float* Ab = A + (size_t)n * 8 * VW + (size_t)v * Vv + tid;
    float a[8];
#pragma unroll
    for (int k = 0; k < 8; ++k) a[k] = Ab[(size_t)k * VW];
    float h2[32];
    mlp12(a, w1, b1, w2, b2, h2);
    const float mask = a[7];
    const float* dp = Dlr + (size_t)n * 64 * Vv + tid;
    float* ap = An + (size_t)n * 64 * VW + (size_t)v * Vv + tid;
#pragma unroll
    for (int o = 0; o < 64; ++o) {
        float t = b3[o];
#pragma unroll
        for (int i = 0; i < 32; ++i) t += w3[o * 32 + i] * h2[i];
        float am = fmaxf(t, 0.f) * mask;
        ap[(size_t)o * VW] = am * dp[(size_t)o * Vv];
    }
}

// ---------------- Kernel 3: out[b,t,w] = sum_v xc[b,t,v]*An[b,v,w] -----------
__global__ __launch_bounds__(256) void k_gemm(const float* __restrict__ xc,
        const float* __restrict__ An, float* __restrict__ out) {
    __shared__ float As[16 * 68];   // [k][t], padded
    __shared__ float Bs[16 * 68];   // [k][w], padded
    const int tid = threadIdx.x;
    const int b = blockIdx.x;
    const int batch = b / 6;            // n*64+o
    const int w0 = (b % 6) * 64;
    const float* Ap = xc + (size_t)batch * TV;        // 64 x 384
    const float* Bp = An + (size_t)batch * VW + w0;   // 384 x 384 (+col offset)
    const int ty = tid / 16, tx = tid % 16;
    const int lr = tid / 4,  lq = tid % 4;   // A-tile loader: row, k-quad
    const int br = tid / 16, bc = tid % 16;  // B-tile loader: k-row, w-quad
    float acc[4][4];
#pragma unroll
    for (int i = 0; i < 4; ++i)
#pragma unroll
        for (int j = 0; j < 4; ++j) acc[i][j] = 0.f;
    for (int k0 = 0; k0 < 384; k0 += 16) {
        float4 a4 = *(const float4*)(Ap + (size_t)lr * 384 + k0 + lq * 4);
        float4 b4 = *(const float4*)(Bp + (size_t)(k0 + br) * 384 + bc * 4);
        As[(lq*4+0)*68 + lr] = a4.x;
        As[(lq*4+1)*68 + lr] = a4.y;
        As[(lq*4+2)*68 + lr] = a4.z;
        As[(lq*4+3)*68 + lr] = a4.w;
        *(float4*)(Bs + br * 68 + bc * 4) = b4;
        __syncthreads();
#pragma unroll
        for (int kk = 0; kk < 16; ++kk) {
            float4 av = *(const float4*)(As + kk * 68 + ty * 4);
            float4 bv = *(const float4*)(Bs + kk * 68 + tx * 4);
            float aa[4] = {av.x, av.y, av.z, av.w};
            float bb[4] = {bv.x, bv.y, bv.z, bv.w};
#pragma unroll
            for (int i = 0; i < 4; ++i)
#pragma unroll
                for (int j = 0; j < 4; ++j) acc[i][j] += aa[i] * bb[j];
        }
        __syncthreads();
    }
    float* op = out + (size_t)batch * TV + w0 + tx * 4;
#pragma unroll
    for (int i = 0; i < 4; ++i) {
        float4 o4 = make_float4(acc[i][0], acc[i][1], acc[i][2], acc[i][3]);
        *(float4*)(op + (size_t)(ty * 4 + i) * 384) = o4;
    }
}

extern "C" void kernel_launch(void* const* d_in, const int* in_sizes, int n_in,
                              void* d_out, int out_size, void* d_ws, size_t ws_size,
                              hipStream_t stream) {
    const float* x  = (const float*)d_in[0];
    const float* A  = (const float*)d_in[1];
    const float* cw = (const float*)d_in[2];
    const float* cb = (const float*)d_in[3];
    const float* w1 = (const float*)d_in[4];
    const float* b1 = (const float*)d_in[5];
    const float* w2 = (const float*)d_in[6];
    const float* b2 = (const float*)d_in[7];
    const float* w3 = (const float*)d_in[8];
    const float* b3 = (const float*)d_in[9];

    float* out = (float*)d_out;
    float* An  = out + OUT0;                 // An output region
    float* xc  = (float*)d_ws;               // 25165824 floats = 100.7 MB
    float* Dl  = xc + OUT0;                  // 393216 floats  = 1.5 MB

    hipMemsetAsync(Dl, 0, (size_t)Nn * 64 * Vv * sizeof(float), stream);
    k_conv<<<768, 256, 0, stream>>>(x, cw, cb, xc);
    k_dl  <<<1536, 128, 0, stream>>>(A, w1, b1, w2, b2, w3, b3, Dl);
    k_rcp <<<1536, 256, 0, stream>>>(Dl);
    k_an  <<<6144, 384, 0, stream>>>(A, w1, b1, w2, b2, w3, b3, Dl, An);
    k_gemm<<<6144, 256, 0, stream>>>(xc, An, out);
}